// Round 13
// baseline (189.930 us; speedup 1.0000x reference)
//
#include <hip/hip_runtime.h>

// Model_47510928228872: 2-layer bidirectional LSTM (H=3) + linear + sigmoid.
// B=8192, T=512, fp32.
//
// Round 13: rounds 5-12 showed the register allocator NEVER keeps a 24-dword
// prefetch buffer live (VGPR_Count ~44 vs ~85 demand) -> loads sink to use,
// ~400cy stall per 8-step block. Fix: distribute the block across the 8
// lanes of each group (lane slot s holds x(t)'s 3 floats; cur+nxt = 6 VGPRs)
// and broadcast per-step operands with compile-time ds_swizzle
// (src = (lane&0x18)|s). Swizzles don't depend on the recurrence ->
// scheduler hides them; 3-reg prefetch is trivially allocatable.
//  K1: l0-fwd + l0-bwd paired (2048 waves = 2/SIMD), gate-split 8-lane cell.
//  K2: l1-fwd + 1-step l1-bwd + head; same lane-distributed block loads.
// y0f/y0b layout [B][64 blk][3 j][8 s], slot t = h(t).

#define B_ 8192
#define T_ 512
#define LOG2E 1.4426950408889634f

typedef float v2f __attribute__((ext_vector_type(2)));

__device__ __forceinline__ float rcp_(float x)  { return __builtin_amdgcn_rcpf(x); }
__device__ __forceinline__ float exp2_(float x) { return __builtin_amdgcn_exp2f(x); }
__device__ __forceinline__ float sigm_(float x) {
  return rcp_(1.0f + exp2_(-LOG2E * x));
}
__device__ __forceinline__ float tanh_(float x) {
  return 1.0f - 2.0f * rcp_(1.0f + exp2_(2.0f * LOG2E * x));
}
__device__ __forceinline__ float act_(float p) { return rcp_(1.f + exp2_(p)); }

__device__ __forceinline__ v2f sp(float s) { return (v2f){s, s}; }
__device__ __forceinline__ v2f pkfma(v2f a, float b, v2f c) {
  return __builtin_elementwise_fma(a, sp(b), c);
}

#define PIN2(v) do {                                                      \
    double _d = __builtin_bit_cast(double, v);                            \
    asm volatile("" : "+v"(_d));                                          \
    v = __builtin_bit_cast(v2f, _d); } while (0)

template <int CTRL>
__device__ __forceinline__ float dppf(float v) {
  int s = __float_as_int(v);
  return __int_as_float(__builtin_amdgcn_update_dpp(s, s, CTRL, 0xF, 0xF, false));
}
#define QP0 dppf<0x00>
#define QP1 dppf<0x55>
#define QP2 dppf<0xAA>
#define SHL4 0x104
#define SHR4 0x114

// Broadcast slot S (0..7) of each 8-lane group: src = (lane & 0x18) | S.
template <int S>
__device__ __forceinline__ float swz8(float v) {
  return __int_as_float(__builtin_amdgcn_ds_swizzle(
      __float_as_int(v), (S << 5) | 0x18));
}

// ============ Kernel 1: layer-0, one direction per wave (gate-split) ========
template <bool DIRB>
__device__ __forceinline__ void l0_dir(
    const float* __restrict__ x,
    const float* __restrict__ Wi, const float* __restrict__ Wh,
    const float* __restrict__ bi, const float* __restrict__ bh,
    float* __restrict__ yout, int b, int lane)
{
  bool qgo = (lane & 4) != 0;           // quad role: (i,f) vs (g,o)
  int j = lane & 3; int jj = (j < 3) ? j : 0;
  int sl = lane & 7;                    // data slot owned by this lane
  const int ra = (qgo ? 6 : 0) + jj, rb = ra + 3;
  const float kx = qgo ? (-2.f * LOG2E) : (-LOG2E);
  const float ky = -LOG2E;
  const float avx = qgo ? 2.f : 1.f;
  const float dvx = qgo ? -1.f : 0.f;

  v2f w0 = {Wi[ra*3+0]*kx, Wi[rb*3+0]*ky},
      w1 = {Wi[ra*3+1]*kx, Wi[rb*3+1]*ky},
      w2 = {Wi[ra*3+2]*kx, Wi[rb*3+2]*ky};
  v2f u0 = {Wh[ra*3+0]*kx, Wh[rb*3+0]*ky},
      u1 = {Wh[ra*3+1]*kx, Wh[rb*3+1]*ky},
      u2 = {Wh[ra*3+2]*kx, Wh[rb*3+2]*ky};
  v2f b2 = {(bi[ra]+bh[ra])*kx, (bi[rb]+bh[rb])*ky};
  PIN2(w0); PIN2(w1); PIN2(w2); PIN2(u0); PIN2(u1); PIN2(u2); PIN2(b2);

  float h = 0.f, c = 0.f, ha0 = 0.f, ha1 = 0.f, ha2 = 0.f;
  float hs0, hs1, hs2, hs3, hs4, hs5, hs6, hs7;

  const float* xrow = x + (size_t)b * (T_ * 3);
  float* ywb = yout + (size_t)b * (T_ * 3) + jj * 8;

  float ax0, ax1, ax2, bx0, bx1, bx2;   // cur/next: 3 floats each

#define LD1(blk, X0, X1, X2) do {                                         \
    const float* _p = xrow + (blk) * 24 + sl * 3;                         \
    X0 = _p[0]; X1 = _p[1]; X2 = _p[2];                                   \
    __builtin_amdgcn_sched_barrier(0); } while (0)

#define STEP1(x0, x1, x2, HOUT) do {                                      \
    v2f pv = pkfma(w0, (x0), b2); pv = pkfma(w1, (x1), pv);               \
    pv = pkfma(w2, (x2), pv);                                             \
    v2f uv = u0 * sp(ha0); uv = pkfma(u1, ha1, uv);                       \
    uv = pkfma(u2, ha2, uv);                                              \
    pv = pv + uv;                                                         \
    float r0v = act_(pv.x);                                               \
    float ayv = act_(pv.y);            /* f (q0) or o (q1) */             \
    float axv = __builtin_fmaf(avx, r0v, dvx); /* i (q0) / tanh g (q1) */ \
    float slx = dppf<SHL4>(axv), sly = dppf<SHL4>(ayv);                   \
    float srx = dppf<SHR4>(axv), sry = dppf<SHR4>(ayv);                   \
    float pig = axv * (qgo ? srx : slx);   /* i*g on both quads */        \
    float gf  = qgo ? sry : ayv;                                          \
    float gO  = qgo ? ayv : sly;                                          \
    c = __builtin_fmaf(gf, c, pig);                                       \
    float th = __builtin_fmaf(                                            \
        2.f, rcp_(1.f + exp2_(-2.f * LOG2E * c)), -1.f);                  \
    h = gO * th;                                                          \
    ha0 = QP0(h); ha1 = QP1(h); ha2 = QP2(h);                             \
    HOUT = h; } while (0)

  // step s: broadcast slot s's x triple to the whole group, then cell step.
#define SS0(X0,X1,X2) STEP1(swz8<0>(X0), swz8<0>(X1), swz8<0>(X2), hs0)
#define SS1(X0,X1,X2) STEP1(swz8<1>(X0), swz8<1>(X1), swz8<1>(X2), hs1)
#define SS2(X0,X1,X2) STEP1(swz8<2>(X0), swz8<2>(X1), swz8<2>(X2), hs2)
#define SS3(X0,X1,X2) STEP1(swz8<3>(X0), swz8<3>(X1), swz8<3>(X2), hs3)
#define SS4(X0,X1,X2) STEP1(swz8<4>(X0), swz8<4>(X1), swz8<4>(X2), hs4)
#define SS5(X0,X1,X2) STEP1(swz8<5>(X0), swz8<5>(X1), swz8<5>(X2), hs5)
#define SS6(X0,X1,X2) STEP1(swz8<6>(X0), swz8<6>(X1), swz8<6>(X2), hs6)
#define SS7(X0,X1,X2) STEP1(swz8<7>(X0), swz8<7>(X1), swz8<7>(X2), hs7)

  // fwd: t ascending; bwd: t descending. hs slot s = h(t = blk*8+s) always.
#define PROC1(X0,X1,X2) do {                                              \
    if (DIRB) {                                                           \
      SS7(X0,X1,X2); SS6(X0,X1,X2); SS5(X0,X1,X2); SS4(X0,X1,X2);         \
      SS3(X0,X1,X2); SS2(X0,X1,X2); SS1(X0,X1,X2); SS0(X0,X1,X2);         \
    } else {                                                              \
      SS0(X0,X1,X2); SS1(X0,X1,X2); SS2(X0,X1,X2); SS3(X0,X1,X2);         \
      SS4(X0,X1,X2); SS5(X0,X1,X2); SS6(X0,X1,X2); SS7(X0,X1,X2);         \
    } } while (0)

#define FLUSH1(blk) do {                                                  \
    if (sl < 3) {                                                         \
      float4* _o = (float4*)(ywb + (blk) * 24);                           \
      _o[0] = make_float4(hs0, hs1, hs2, hs3);                            \
      _o[1] = make_float4(hs4, hs5, hs6, hs7);                            \
    } } while (0)

#define BLK(k) (DIRB ? (63 - (k)) : (k))

  LD1(BLK(0), ax0, ax1, ax2);
  LD1(BLK(1), bx0, bx1, bx2);
  for (int k = 0; k < 64; k += 2) {
    PROC1(ax0, ax1, ax2);
    FLUSH1(BLK(k));
    if (k + 2 < 64) LD1(BLK(k + 2), ax0, ax1, ax2);
    PROC1(bx0, bx1, bx2);
    FLUSH1(BLK(k + 1));
    if (k + 3 < 64) LD1(BLK(k + 3), bx0, bx1, bx2);
  }
#undef LD1
#undef STEP1
#undef SS0
#undef SS1
#undef SS2
#undef SS3
#undef SS4
#undef SS5
#undef SS6
#undef SS7
#undef PROC1
#undef FLUSH1
#undef BLK
}

__global__ __launch_bounds__(256, 2) void lstm_l0_pair(
    const float* __restrict__ x,
    const float* __restrict__ Wf_ih, const float* __restrict__ Wf_hh,
    const float* __restrict__ bf_ih, const float* __restrict__ bf_hh,
    const float* __restrict__ Wr_ih, const float* __restrict__ Wr_hh,
    const float* __restrict__ br_ih, const float* __restrict__ br_hh,
    float* __restrict__ y0f, float* __restrict__ y0b)
{
  int gid = blockIdx.x * 256 + threadIdx.x;
  const int nfwd = B_ * 8;             // multiple of 256 -> wave-uniform split
  if (gid < nfwd) {
    l0_dir<false>(x, Wf_ih, Wf_hh, bf_ih, bf_hh, y0f, gid >> 3, gid & 7);
  } else {
    int g2 = gid - nfwd;
    l0_dir<true>(x, Wr_ih, Wr_hh, br_ih, br_hh, y0b, g2 >> 3, g2 & 7);
  }
}

// ======= Kernel 2: layer-1 fwd + epilogue (lane-distributed loads) ==========
#define CELL_TAIL(HOUT)                                                   \
    float r0v = act_(pv.x);                                               \
    float ayv = act_(pv.y);                                               \
    float axv = __builtin_fmaf(avx, r0v, dvx);                            \
    float slx = dppf<SHL4>(axv), sly = dppf<SHL4>(ayv);                   \
    float srx = dppf<SHR4>(axv), sry = dppf<SHR4>(ayv);                   \
    float pig = axv * (qgo ? srx : slx);                                  \
    float gf  = qgo ? sry : ayv;                                          \
    float gO  = qgo ? ayv : sly;                                          \
    c = __builtin_fmaf(gf, c, pig);                                       \
    float th = __builtin_fmaf(                                            \
        2.f, rcp_(1.f + exp2_(-2.f * LOG2E * c)), -1.f);                  \
    h = gO * th;                                                          \
    ha0 = QP0(h); ha1 = QP1(h); ha2 = QP2(h);                             \
    HOUT = h;

__global__ __launch_bounds__(256) void lstm_l1_fwd(
    const float* __restrict__ Wih1, const float* __restrict__ Whh1,
    const float* __restrict__ bih1, const float* __restrict__ bhh1,
    const float* __restrict__ Wih1r,
    const float* __restrict__ bih1r, const float* __restrict__ bhh1r,
    const float* __restrict__ Wlin, const float* __restrict__ blin,
    const float* __restrict__ y0f, const float* __restrict__ y0b,
    float* __restrict__ out)
{
  int tid  = blockIdx.x * 256 + threadIdx.x;
  int b    = tid >> 3;
  int lane = tid & 7;
  bool qgo = (lane & 4) != 0;
  int j = lane & 3; int jj = (j < 3) ? j : 0;
  int sl = lane & 7;
  const int ra = (qgo ? 6 : 0) + jj, rb = ra + 3;
  const float kx = qgo ? (-2.f * LOG2E) : (-LOG2E);
  const float ky = -LOG2E;
  const float avx = qgo ? 2.f : 1.f;
  const float dvx = qgo ? -1.f : 0.f;

  v2f w0 = {Wih1[ra*6+0]*kx, Wih1[rb*6+0]*ky},
      w1 = {Wih1[ra*6+1]*kx, Wih1[rb*6+1]*ky},
      w2 = {Wih1[ra*6+2]*kx, Wih1[rb*6+2]*ky},
      w3 = {Wih1[ra*6+3]*kx, Wih1[rb*6+3]*ky},
      w4 = {Wih1[ra*6+4]*kx, Wih1[rb*6+4]*ky},
      w5 = {Wih1[ra*6+5]*kx, Wih1[rb*6+5]*ky};
  v2f u0 = {Whh1[ra*3+0]*kx, Whh1[rb*3+0]*ky},
      u1 = {Whh1[ra*3+1]*kx, Whh1[rb*3+1]*ky},
      u2 = {Whh1[ra*3+2]*kx, Whh1[rb*3+2]*ky};
  v2f b2 = {(bih1[ra]+bhh1[ra])*kx, (bih1[rb]+bhh1[rb])*ky};
  PIN2(w0); PIN2(w1); PIN2(w2); PIN2(w3); PIN2(w4); PIN2(w5);
  PIN2(u0); PIN2(u1); PIN2(u2); PIN2(b2);

  const float* yfr = y0f + (size_t)b * (T_ * 3);
  const float* ybr = y0b + (size_t)b * (T_ * 3);

  float h = 0.f, c = 0.f, ha0 = 0.f, ha1 = 0.f, ha2 = 0.f;
  float hs0, hs1, hs2, hs3, hs4, hs5, hs6, hs7;
  float af0, af1, af2, ag0, ag1, ag2;   // cur block: slot's f/g triples
  float bf0, bf1, bf2, bg0, bg1, bg2;   // next block

#define LDB(blk, F0,F1,F2, G0,G1,G2) do {                                 \
    const float* _f = yfr + (blk) * 24 + sl;                              \
    const float* _g = ybr + (blk) * 24 + sl;                              \
    F0 = _f[0]; F1 = _f[8]; F2 = _f[16];                                  \
    G0 = _g[0]; G1 = _g[8]; G2 = _g[16];                                  \
    __builtin_amdgcn_sched_barrier(0); } while (0)

#define STEPB(f0, f1, f2, g0, g1, g2, HOUT) do {                          \
    v2f pv = pkfma(w0, (f0), b2); pv = pkfma(w1, (f1), pv);               \
    pv = pkfma(w2, (f2), pv);                                             \
    v2f nv = w3 * sp(g0); nv = pkfma(w4, (g1), nv);                       \
    nv = pkfma(w5, (g2), nv);                                             \
    v2f uv = u0 * sp(ha0); uv = pkfma(u1, ha1, uv);                       \
    uv = pkfma(u2, ha2, uv);                                              \
    pv = (pv + nv) + uv;                                                  \
    CELL_TAIL(HOUT) } while (0)

#define SB(s, HS, F0,F1,F2, G0,G1,G2)                                     \
    STEPB(swz8<s>(F0), swz8<s>(F1), swz8<s>(F2),                          \
          swz8<s>(G0), swz8<s>(G1), swz8<s>(G2), HS)

#define PROCB(F0,F1,F2, G0,G1,G2) do {                                    \
    SB(0, hs0, F0,F1,F2, G0,G1,G2);                                       \
    SB(1, hs1, F0,F1,F2, G0,G1,G2);                                       \
    SB(2, hs2, F0,F1,F2, G0,G1,G2);                                       \
    SB(3, hs3, F0,F1,F2, G0,G1,G2);                                       \
    SB(4, hs4, F0,F1,F2, G0,G1,G2);                                       \
    SB(5, hs5, F0,F1,F2, G0,G1,G2);                                       \
    SB(6, hs6, F0,F1,F2, G0,G1,G2);                                       \
    SB(7, hs7, F0,F1,F2, G0,G1,G2); } while (0)

  LDB(0, af0,af1,af2, ag0,ag1,ag2);
  LDB(1, bf0,bf1,bf2, bg0,bg1,bg2);
  for (int it = 0; it < 32; ++it) {
    PROCB(af0,af1,af2, ag0,ag1,ag2);
    if (it < 31) LDB(2*it+2, af0,af1,af2, ag0,ag1,ag2);
    PROCB(bf0,bf1,bf2, bg0,bg1,bg2);
    if (it < 31) LDB(2*it+3, bf0,bf1,bf2, bg0,bg1,bg2);
  }
  (void)hs0; (void)hs1; (void)hs2; (void)hs3;
  (void)hs4; (void)hs5; (void)hs6; (void)hs7;
  // h = h1_fwd[j](T-1) on all lanes.

  // Epilogue inputs y0(T-1): block 63, slot 7, j-planes 0,8,16.
  const float* ufp = yfr + 63 * 24 + 7;
  const float* ubp = ybr + 63 * 24 + 7;
  float uf0 = ufp[0], uf1 = ufp[8], uf2 = ufp[16];
  float ub0 = ubp[0], ub1 = ubp[8], ub2 = ubp[16];

  float h1b;
  {
    v2f r0 = {Wih1r[ra*6+0]*kx, Wih1r[rb*6+0]*ky},
        r1 = {Wih1r[ra*6+1]*kx, Wih1r[rb*6+1]*ky},
        r2 = {Wih1r[ra*6+2]*kx, Wih1r[rb*6+2]*ky},
        r3 = {Wih1r[ra*6+3]*kx, Wih1r[rb*6+3]*ky},
        r4 = {Wih1r[ra*6+4]*kx, Wih1r[rb*6+4]*ky},
        r5 = {Wih1r[ra*6+5]*kx, Wih1r[rb*6+5]*ky};
    v2f br = {(bih1r[ra]+bhh1r[ra])*kx, (bih1r[rb]+bhh1r[rb])*ky};
    v2f qv = pkfma(r0, uf0, br); qv = pkfma(r1, uf1, qv);
    qv = pkfma(r2, uf2, qv);     qv = pkfma(r3, ub0, qv);
    qv = pkfma(r4, ub1, qv);     qv = pkfma(r5, ub2, qv);
    float r0v = act_(qv.x);
    float ayv = act_(qv.y);
    float axv = __builtin_fmaf(avx, r0v, dvx);
    float slx = dppf<SHL4>(axv), sly = dppf<SHL4>(ayv);
    float srx = dppf<SHR4>(axv);
    float gi = qgo ? srx : axv;
    float gG = qgo ? axv : slx;
    float gO = qgo ? ayv : sly;
    float cb = gi * gG;
    h1b = gO * tanh_(cb);
  }

  float part = 0.f;
  if (!qgo && j < 3) part = __builtin_fmaf(Wlin[j], h, Wlin[3 + j] * h1b);
  part += __shfl_xor(part, 1, 8);
  part += __shfl_xor(part, 2, 8);
  part += __shfl_xor(part, 4, 8);
  if (lane == 0) out[b] = sigm_(part + blin[0]);
#undef LDB
#undef STEPB
#undef SB
#undef PROCB
}

extern "C" void kernel_launch(void* const* d_in, const int* in_sizes, int n_in,
                              void* d_out, int out_size, void* d_ws, size_t ws_size,
                              hipStream_t stream) {
  const float* x        = (const float*)d_in[0];
  const float* W_ih_l0  = (const float*)d_in[1];
  const float* W_hh_l0  = (const float*)d_in[2];
  const float* b_ih_l0  = (const float*)d_in[3];
  const float* b_hh_l0  = (const float*)d_in[4];
  const float* W_ih_l0r = (const float*)d_in[5];
  const float* W_hh_l0r = (const float*)d_in[6];
  const float* b_ih_l0r = (const float*)d_in[7];
  const float* b_hh_l0r = (const float*)d_in[8];
  const float* W_ih_l1  = (const float*)d_in[9];
  const float* W_hh_l1  = (const float*)d_in[10];
  const float* b_ih_l1  = (const float*)d_in[11];
  const float* b_hh_l1  = (const float*)d_in[12];
  const float* W_ih_l1r = (const float*)d_in[13];
  const float* b_ih_l1r = (const float*)d_in[15];
  const float* b_hh_l1r = (const float*)d_in[16];
  const float* W_lin    = (const float*)d_in[17];
  const float* b_lin    = (const float*)d_in[18];

  float* y0f = (float*)d_ws;                        // 48 MB
  float* y0b = (float*)d_ws + (size_t)B_ * T_ * 3;  // 48 MB
  float* out = (float*)d_out;

  // K1: fwd stream + bwd stream = 2048 waves (2/SIMD)
  lstm_l0_pair<<<(B_ * 8 * 2) / 256, 256, 0, stream>>>(
      x, W_ih_l0, W_hh_l0, b_ih_l0, b_hh_l0,
      W_ih_l0r, W_hh_l0r, b_ih_l0r, b_hh_l0r, y0f, y0b);

  // K2: 8 lanes/batch = 1024 waves
  lstm_l1_fwd<<<(B_ * 8) / 256, 256, 0, stream>>>(
      W_ih_l1, W_hh_l1, b_ih_l1, b_hh_l1,
      W_ih_l1r, b_ih_l1r, b_hh_l1r,
      W_lin, b_lin, y0f, y0b, out);
}

// Round 14
// 143.055 us; speedup vs baseline: 1.3277x; 1.3277x over previous
//
#include <hip/hip_runtime.h>

// Model_47510928228872: 2-layer bidirectional LSTM (H=3) + linear + sigmoid.
// B=8192, T=512, fp32.
//
// Round 14 = round 8 (best measured: 142.6us) + PIN2 on all loop-invariant
// weight registers (r11 evidence: pins prevent in-loop weight reloads, ~5%).
//  K1 (l0-bwd): gate-split 8-lane cell (quad0=(i,f), quad1=(g,o), prescaled
//      rows, DPP exchange, both quads update c,h), double-buffered blocks,
//      shifted store: y0b [B][64][3][8], slot t+1 holds h_bwd(t).
//  K2 (l0f+l1f fused): 8 lanes/batch, quad0=l0 cell, quad1=l1 cell lagging
//      one step (stagger absorbed by shifted y0b layout), 1-step l1-bwd
//      epilogue + linear + sigmoid head.

#define B_ 8192
#define T_ 512
#define LOG2E 1.4426950408889634f

typedef float v2f __attribute__((ext_vector_type(2)));

__device__ __forceinline__ float rcp_(float x)  { return __builtin_amdgcn_rcpf(x); }
__device__ __forceinline__ float exp2_(float x) { return __builtin_amdgcn_exp2f(x); }
__device__ __forceinline__ float sigm_(float x) {
  return rcp_(1.0f + exp2_(-LOG2E * x));
}
__device__ __forceinline__ float tanh_(float x) {
  return 1.0f - 2.0f * rcp_(1.0f + exp2_(2.0f * LOG2E * x));
}
// activation on PRESCALED preact: rcp(1+exp2(p))
__device__ __forceinline__ float act_(float p) { return rcp_(1.f + exp2_(p)); }

__device__ __forceinline__ v2f sp(float s) { return (v2f){s, s}; }
__device__ __forceinline__ v2f pkfma(v2f a, float b, v2f c) {
  return __builtin_elementwise_fma(a, sp(b), c);
}

// Pin a value: defined by opaque asm -> cannot be rematerialized/reloaded.
#define PIN2(v) do {                                                      \
    double _d = __builtin_bit_cast(double, v);                            \
    asm volatile("" : "+v"(_d));                                          \
    v = __builtin_bit_cast(v2f, _d); } while (0)

template <int CTRL>
__device__ __forceinline__ float dppf(float v) {
  int s = __float_as_int(v);
  return __int_as_float(__builtin_amdgcn_update_dpp(s, s, CTRL, 0xF, 0xF, false));
}
#define QB0 0x00   // quad_perm broadcast lane0 of quad
#define QB1 0x55
#define QB2 0xAA
#define SHL4 0x104 // row_shl:4 (lane i <- i+4)
#define SHR4 0x114 // row_shr:4 (lane i <- i-4)

// ---------------- Kernel 1: layer-0 backward (8 lanes/batch) ----------------
__global__ __launch_bounds__(256, 1) void lstm_l0_bwd(
    const float* __restrict__ x,      // [B][T][3]
    const float* __restrict__ Wih, const float* __restrict__ Whh,
    const float* __restrict__ bih, const float* __restrict__ bhh,
    float* __restrict__ y0b)          // [B][64][3][8], slot t+1 holds h_bwd(t)
{
  int tid = blockIdx.x * 256 + threadIdx.x;
  int b = tid >> 3, lane = tid & 7;
  bool qgo = (lane & 4) != 0;         // quad role: false=(i,f), true=(g,o)
  int j = lane & 3; int jj = (j < 3) ? j : 0;
  const int ra = (qgo ? 6 : 0) + jj, rb = ra + 3;
  // Prescale: row_a by kx (g-row -2L, i-row -L), row_b by ky (-L).
  const float kx = qgo ? (-2.f * LOG2E) : (-LOG2E);
  const float ky = -LOG2E;

  v2f w0 = {Wih[ra*3+0]*kx, Wih[rb*3+0]*ky},
      w1 = {Wih[ra*3+1]*kx, Wih[rb*3+1]*ky},
      w2 = {Wih[ra*3+2]*kx, Wih[rb*3+2]*ky};
  v2f u0 = {Whh[ra*3+0]*kx, Whh[rb*3+0]*ky},
      u1 = {Whh[ra*3+1]*kx, Whh[rb*3+1]*ky},
      u2 = {Whh[ra*3+2]*kx, Whh[rb*3+2]*ky};
  v2f b2 = {(bih[ra]+bhh[ra])*kx, (bih[rb]+bhh[rb])*ky};
  PIN2(w0); PIN2(w1); PIN2(w2);
  PIN2(u0); PIN2(u1); PIN2(u2); PIN2(b2);
  const float avx = qgo ? 2.f : 1.f;
  const float dvx = qgo ? -1.f : 0.f;

  float h = 0.f, c = 0.f, ha0 = 0.f, ha1 = 0.f, ha2 = 0.f;
  const float4* xq = (const float4*)(x + (size_t)b * (T_ * 3));
  float* ywb = y0b + (size_t)b * (T_ * 3) + jj * 8;

  float hs0 = 0.f, hs1 = 0.f, hs2 = 0.f, hs3 = 0.f,
        hs4 = 0.f, hs5 = 0.f, hs6 = 0.f, hs7 = 0.f, h511 = 0.f;
  float4 p0, p1, p2, p3, p4, p5, q0, q1, q2, q3, q4, q5;

#define LD1(blk, r0_, r1_, r2_, r3_, r4_, r5_) do {                       \
    const float4* _p = xq + (blk) * 6;                                    \
    r0_ = _p[0]; r1_ = _p[1]; r2_ = _p[2];                                \
    r3_ = _p[3]; r4_ = _p[4]; r5_ = _p[5];                                \
    __builtin_amdgcn_sched_barrier(0); } while (0)

#define STEP1(x0, x1, x2, HOUT) do {                                      \
    v2f pv = pkfma(w0, (x0), b2); pv = pkfma(w1, (x1), pv);               \
    pv = pkfma(w2, (x2), pv);                                             \
    v2f uv = u0 * sp(ha0); uv = pkfma(u1, ha1, uv);                       \
    uv = pkfma(u2, ha2, uv);                                              \
    pv = pv + uv;                                                         \
    float r0v = act_(pv.x);                                               \
    float ayv = act_(pv.y);            /* f (q0) or o (q1) */             \
    float axv = __builtin_fmaf(avx, r0v, dvx); /* i (q0) / tanh g (q1) */ \
    float slx = dppf<SHL4>(axv), sly = dppf<SHL4>(ayv);                   \
    float srx = dppf<SHR4>(axv), sry = dppf<SHR4>(ayv);                   \
    float pig = axv * (qgo ? srx : slx);   /* i*g on both quads */        \
    float gf  = qgo ? sry : ayv;                                          \
    float gO  = qgo ? ayv : sly;                                          \
    c = __builtin_fmaf(gf, c, pig);                                       \
    float th = __builtin_fmaf(                                            \
        2.f, rcp_(1.f + exp2_(-2.f * LOG2E * c)), -1.f);                  \
    h = gO * th;                                                          \
    ha0 = dppf<QB0>(h); ha1 = dppf<QB1>(h); ha2 = dppf<QB2>(h);           \
    HOUT = h; } while (0)

#define FLUSH1(yblk) do {                                                 \
    if (lane < 3) {                                                       \
      float4* _o = (float4*)(ywb + (yblk) * 24);                          \
      _o[0] = make_float4(hs0, hs1, hs2, hs3);                            \
      _o[1] = make_float4(hs4, hs5, hs6, hs7);                            \
    } } while (0)

#define PROC1(blk, r0_, r1_, r2_, r3_, r4_, r5_, FIRST) do {              \
    STEP1(r5_.y, r5_.z, r5_.w, hs0);                                      \
    if (FIRST) h511 = hs0; else FLUSH1((blk) + 1);                        \
    STEP1(r4_.z, r4_.w, r5_.x, hs7);                                      \
    STEP1(r3_.w, r4_.x, r4_.y, hs6);                                      \
    STEP1(r3_.x, r3_.y, r3_.z, hs5);                                      \
    STEP1(r2_.y, r2_.z, r2_.w, hs4);                                      \
    STEP1(r1_.z, r1_.w, r2_.x, hs3);                                      \
    STEP1(r0_.w, r1_.x, r1_.y, hs2);                                      \
    STEP1(r0_.x, r0_.y, r0_.z, hs1); } while (0)

  LD1(63, p0, p1, p2, p3, p4, p5);
  LD1(62, q0, q1, q2, q3, q4, q5);
  PROC1(63, p0, p1, p2, p3, p4, p5, true);
  LD1(61, p0, p1, p2, p3, p4, p5);
  PROC1(62, q0, q1, q2, q3, q4, q5, false);
  LD1(60, q0, q1, q2, q3, q4, q5);
  for (int blk = 61; blk >= 1; blk -= 2) {
    PROC1(blk, p0, p1, p2, p3, p4, p5, false);
    if (blk >= 3) LD1(blk - 2, p0, p1, p2, p3, p4, p5);
    PROC1(blk - 1, q0, q1, q2, q3, q4, q5, false);
    if (blk >= 3) LD1(blk - 3, q0, q1, q2, q3, q4, q5);
  }
  hs0 = h511;
  FLUSH1(0);
#undef LD1
#undef STEP1
#undef FLUSH1
#undef PROC1
}

// ------------- Kernel 2: l0-fwd + l1-fwd fused (8 lanes/batch) --------------
__global__ __launch_bounds__(256, 1) void lstm_fused_fwd(
    const float* __restrict__ x,
    const float* __restrict__ Wih0, const float* __restrict__ Whh0,
    const float* __restrict__ bih0, const float* __restrict__ bhh0,
    const float* __restrict__ Wih1, const float* __restrict__ Whh1,
    const float* __restrict__ bih1, const float* __restrict__ bhh1,
    const float* __restrict__ Wih1r, const float* __restrict__ Whh1r,
    const float* __restrict__ bih1r, const float* __restrict__ bhh1r,
    const float* __restrict__ Wlin, const float* __restrict__ blin,
    const float* __restrict__ y0b,   // [B][64][3][8] shifted
    float* __restrict__ out)         // [B]
{
  int tid = blockIdx.x * 256 + threadIdx.x;
  int b = tid >> 3, lane = tid & 7;
  bool role1 = lane >= 4;               // quad 1 = layer-1 cell
  int j  = role1 ? (lane - 4) : lane;
  int jc = (j < 3) ? j : 2;
  const int r0 = jc, r1 = 3 + jc, r2 = 6 + jc, r3 = 9 + jc;
  const float sI = -LOG2E, sG = -2.f * LOG2E;

  // wif = (i-row, f-row) scaled (sI,sI); wgo = (g-row, o-row) (sG,sI).
  v2f wif0, wif1, wif2, wif3, wif4, wif5, wif6, wif7, wif8;
  v2f wgo0, wgo1, wgo2, wgo3, wgo4, wgo5, wgo6, wgo7, wgo8;
  v2f bif, bgo;
  if (!role1) {
    wif0 = (v2f){Wih0[r0*3+0]*sI, Wih0[r1*3+0]*sI};
    wif1 = (v2f){Wih0[r0*3+1]*sI, Wih0[r1*3+1]*sI};
    wif2 = (v2f){Wih0[r0*3+2]*sI, Wih0[r1*3+2]*sI};
    wif3 = (v2f){0.f, 0.f}; wif4 = (v2f){0.f, 0.f}; wif5 = (v2f){0.f, 0.f};
    wif6 = (v2f){Whh0[r0*3+0]*sI, Whh0[r1*3+0]*sI};
    wif7 = (v2f){Whh0[r0*3+1]*sI, Whh0[r1*3+1]*sI};
    wif8 = (v2f){Whh0[r0*3+2]*sI, Whh0[r1*3+2]*sI};
    wgo0 = (v2f){Wih0[r2*3+0]*sG, Wih0[r3*3+0]*sI};
    wgo1 = (v2f){Wih0[r2*3+1]*sG, Wih0[r3*3+1]*sI};
    wgo2 = (v2f){Wih0[r2*3+2]*sG, Wih0[r3*3+2]*sI};
    wgo3 = (v2f){0.f, 0.f}; wgo4 = (v2f){0.f, 0.f}; wgo5 = (v2f){0.f, 0.f};
    wgo6 = (v2f){Whh0[r2*3+0]*sG, Whh0[r3*3+0]*sI};
    wgo7 = (v2f){Whh0[r2*3+1]*sG, Whh0[r3*3+1]*sI};
    wgo8 = (v2f){Whh0[r2*3+2]*sG, Whh0[r3*3+2]*sI};
    bif = (v2f){(bih0[r0]+bhh0[r0])*sI, (bih0[r1]+bhh0[r1])*sI};
    bgo = (v2f){(bih0[r2]+bhh0[r2])*sG, (bih0[r3]+bhh0[r3])*sI};
  } else {
    wif0 = (v2f){Wih1[r0*6+0]*sI, Wih1[r1*6+0]*sI};
    wif1 = (v2f){Wih1[r0*6+1]*sI, Wih1[r1*6+1]*sI};
    wif2 = (v2f){Wih1[r0*6+2]*sI, Wih1[r1*6+2]*sI};
    wif3 = (v2f){Wih1[r0*6+3]*sI, Wih1[r1*6+3]*sI};
    wif4 = (v2f){Wih1[r0*6+4]*sI, Wih1[r1*6+4]*sI};
    wif5 = (v2f){Wih1[r0*6+5]*sI, Wih1[r1*6+5]*sI};
    wif6 = (v2f){Whh1[r0*3+0]*sI, Whh1[r1*3+0]*sI};
    wif7 = (v2f){Whh1[r0*3+1]*sI, Whh1[r1*3+1]*sI};
    wif8 = (v2f){Whh1[r0*3+2]*sI, Whh1[r1*3+2]*sI};
    wgo0 = (v2f){Wih1[r2*6+0]*sG, Wih1[r3*6+0]*sI};
    wgo1 = (v2f){Wih1[r2*6+1]*sG, Wih1[r3*6+1]*sI};
    wgo2 = (v2f){Wih1[r2*6+2]*sG, Wih1[r3*6+2]*sI};
    wgo3 = (v2f){Wih1[r2*6+3]*sG, Wih1[r3*6+3]*sI};
    wgo4 = (v2f){Wih1[r2*6+4]*sG, Wih1[r3*6+4]*sI};
    wgo5 = (v2f){Wih1[r2*6+5]*sG, Wih1[r3*6+5]*sI};
    wgo6 = (v2f){Whh1[r2*3+0]*sG, Whh1[r3*3+0]*sI};
    wgo7 = (v2f){Whh1[r2*3+1]*sG, Whh1[r3*3+1]*sI};
    wgo8 = (v2f){Whh1[r2*3+2]*sG, Whh1[r3*3+2]*sI};
    bif = (v2f){(bih1[r0]+bhh1[r0])*sI, (bih1[r1]+bhh1[r1])*sI};
    bgo = (v2f){(bih1[r2]+bhh1[r2])*sG, (bih1[r3]+bhh1[r3])*sI};
  }
  PIN2(wif0); PIN2(wif1); PIN2(wif2); PIN2(wif3); PIN2(wif4);
  PIN2(wif5); PIN2(wif6); PIN2(wif7); PIN2(wif8);
  PIN2(wgo0); PIN2(wgo1); PIN2(wgo2); PIN2(wgo3); PIN2(wgo4);
  PIN2(wgo5); PIN2(wgo6); PIN2(wgo7); PIN2(wgo8);
  PIN2(bif); PIN2(bgo);

  float h = 0.f, c = 0.f;
  float ha0 = 0.f, ha1 = 0.f, ha2 = 0.f;  // own cell h(t-1)
  float hb0 = 0.f, hb1 = 0.f, hb2 = 0.f;  // l0 cell h(t-1) (for role1)
  const float4* baseq =
      (const float4*)((role1 ? y0b : x) + (size_t)b * (T_ * 3));

  // y0b block 0 slot 0 = h_bwd(T-1)[j] at j-plane offsets 0,8,16.
  const float* up = y0b + (size_t)b * (T_ * 3);
  float ub0 = up[0], ub1 = up[8], ub2 = up[16];

  float4 p0, p1, p2, p3, p4, p5, q0, q1, q2, q3, q4, q5;

#define LD2(blk, r0_, r1_, r2_, r3_, r4_, r5_) do {                       \
    const float4* _p = baseq + (blk) * 6;                                 \
    r0_ = _p[0]; r1_ = _p[1]; r2_ = _p[2];                                \
    r3_ = _p[3]; r4_ = _p[4]; r5_ = _p[5];                                \
    __builtin_amdgcn_sched_barrier(0); } while (0)

#define GATES2(m0, m1, m2, n0, n1, n2) /* -> cn, hn */                    \
    float v0 = role1 ? hb0 : (m0);                                        \
    float v1 = role1 ? hb1 : (m1);                                        \
    float v2 = role1 ? hb2 : (m2);                                        \
    v2f aif = pkfma(wif0, v0, bif); aif = pkfma(wif1, v1, aif);           \
    aif = pkfma(wif2, v2, aif);                                           \
    v2f nif = wif3 * sp(n0); nif = pkfma(wif4, (n1), nif);                \
    nif = pkfma(wif5, (n2), nif);                                         \
    v2f uif = wif6 * sp(ha0); uif = pkfma(wif7, ha1, uif);                \
    uif = pkfma(wif8, ha2, uif);                                          \
    v2f pif = (aif + nif) + uif;                                          \
    v2f ago = pkfma(wgo0, v0, bgo); ago = pkfma(wgo1, v1, ago);           \
    ago = pkfma(wgo2, v2, ago);                                           \
    v2f ngo = wgo3 * sp(n0); ngo = pkfma(wgo4, (n1), ngo);                \
    ngo = pkfma(wgo5, (n2), ngo);                                         \
    v2f ugo = wgo6 * sp(ha0); ugo = pkfma(wgo7, ha1, ugo);                \
    ugo = pkfma(wgo8, ha2, ugo);                                          \
    v2f pgo = (ago + ngo) + ugo;                                          \
    float ig = act_(pif.x);                                               \
    float fg = act_(pif.y);                                               \
    float gg = __builtin_fmaf(2.f, act_(pgo.x), -1.f);                    \
    float og = act_(pgo.y);                                               \
    float cn = __builtin_fmaf(fg, c, ig * gg);                            \
    float th = __builtin_fmaf(                                            \
        2.f, rcp_(1.f + exp2_(-2.f * LOG2E * cn)), -1.f);                 \
    float hn = og * th;

#define BCAST2() do {                                                     \
    ha0 = dppf<QB0>(h); ha1 = dppf<QB1>(h); ha2 = dppf<QB2>(h);           \
    hb0 = dppf<SHR4>(ha0); hb1 = dppf<SHR4>(ha1); hb2 = dppf<SHR4>(ha2);  \
  } while (0)

#define STEP2(m0, m1, m2, n0, n1, n2) do {                                \
    GATES2(m0, m1, m2, n0, n1, n2)                                        \
    c = cn; h = hn;                                                       \
    BCAST2(); } while (0)

#define STEP2V(m0, m1, m2, n0, n1, n2, VALID) do {                        \
    GATES2(m0, m1, m2, n0, n1, n2)                                        \
    c = (VALID) ? cn : c; h = (VALID) ? hn : h;                           \
    BCAST2(); } while (0)

  // role0 reads its block as [8 s][3 k]; role1 as [3 j][8 s].
#define PROC2(r0_, r1_, r2_, r3_, r4_, r5_) do {                          \
    STEP2(r0_.x, r0_.y, r0_.z,  r0_.x, r2_.x, r4_.x);                     \
    STEP2(r0_.w, r1_.x, r1_.y,  r0_.y, r2_.y, r4_.y);                     \
    STEP2(r1_.z, r1_.w, r2_.x,  r0_.z, r2_.z, r4_.z);                     \
    STEP2(r2_.y, r2_.z, r2_.w,  r0_.w, r2_.w, r4_.w);                     \
    STEP2(r3_.x, r3_.y, r3_.z,  r1_.x, r3_.x, r5_.x);                     \
    STEP2(r3_.w, r4_.x, r4_.y,  r1_.y, r3_.y, r5_.y);                     \
    STEP2(r4_.z, r4_.w, r5_.x,  r1_.z, r3_.z, r5_.z);                     \
    STEP2(r5_.y, r5_.z, r5_.w,  r1_.w, r3_.w, r5_.w); } while (0)

  LD2(0, p0, p1, p2, p3, p4, p5);
  LD2(1, q0, q1, q2, q3, q4, q5);
  // Block 0 peeled: step tt=0 invalid for role1 (it lags one step).
  STEP2V(p0.x, p0.y, p0.z,  p0.x, p2.x, p4.x, !role1);
  STEP2(p0.w, p1.x, p1.y,  p0.y, p2.y, p4.y);
  STEP2(p1.z, p1.w, p2.x,  p0.z, p2.z, p4.z);
  STEP2(p2.y, p2.z, p2.w,  p0.w, p2.w, p4.w);
  STEP2(p3.x, p3.y, p3.z,  p1.x, p3.x, p5.x);
  STEP2(p3.w, p4.x, p4.y,  p1.y, p3.y, p5.y);
  STEP2(p4.z, p4.w, p5.x,  p1.z, p3.z, p5.z);
  STEP2(p5.y, p5.z, p5.w,  p1.w, p3.w, p5.w);
  LD2(2, p0, p1, p2, p3, p4, p5);
  PROC2(q0, q1, q2, q3, q4, q5);
  LD2(3, q0, q1, q2, q3, q4, q5);
  for (int blk = 2; blk < 64; blk += 2) {
    PROC2(p0, p1, p2, p3, p4, p5);
    if (blk + 2 < 64) LD2(blk + 2, p0, p1, p2, p3, p4, p5);
    PROC2(q0, q1, q2, q3, q4, q5);
    if (blk + 3 < 64) LD2(blk + 3, q0, q1, q2, q3, q4, q5);
  }
  // Final step tt=512: role1 processes t=T-1 (inputs hb + ub); role0 frozen.
  STEP2V(ub0, ub1, ub2,  ub0, ub1, ub2, role1);
  // role1 lanes 4-6: h = h1_fwd[j](T-1). ha(role0)/hb(role1) = h0_fwd(T-1).

  float e0 = role1 ? hb0 : ha0;
  float e1 = role1 ? hb1 : ha1;
  float e2 = role1 ? hb2 : ha2;

  // Layer-1 backward: one step from zero state (raw weights, all lanes).
  float h1b;
  {
    float q_i = bih1r[r0] + bhh1r[r0]
              + Wih1r[r0*6+0]*e0 + Wih1r[r0*6+1]*e1 + Wih1r[r0*6+2]*e2
              + Wih1r[r0*6+3]*ub0 + Wih1r[r0*6+4]*ub1 + Wih1r[r0*6+5]*ub2;
    float q_g = bih1r[r2] + bhh1r[r2]
              + Wih1r[r2*6+0]*e0 + Wih1r[r2*6+1]*e1 + Wih1r[r2*6+2]*e2
              + Wih1r[r2*6+3]*ub0 + Wih1r[r2*6+4]*ub1 + Wih1r[r2*6+5]*ub2;
    float q_o = bih1r[r3] + bhh1r[r3]
              + Wih1r[r3*6+0]*e0 + Wih1r[r3*6+1]*e1 + Wih1r[r3*6+2]*e2
              + Wih1r[r3*6+3]*ub0 + Wih1r[r3*6+4]*ub1 + Wih1r[r3*6+5]*ub2;
    float ig = sigm_(q_i), gg = tanh_(q_g), og = sigm_(q_o);
    h1b = og * tanh_(ig * gg);          // c_prev = 0 -> f-gate drops out
  }

  float part = 0.f;
  if (role1) { if (j < 3) part = Wlin[j]     * h;   }
  else       { if (j < 3) part = Wlin[3 + j] * h1b; }
  part += __shfl_xor(part, 1, 8);
  part += __shfl_xor(part, 2, 8);
  part += __shfl_xor(part, 4, 8);
  if (lane == 0) out[b] = sigm_(part + blin[0]);
#undef LD2
#undef GATES2
#undef BCAST2
#undef STEP2
#undef STEP2V
#undef PROC2
}

extern "C" void kernel_launch(void* const* d_in, const int* in_sizes, int n_in,
                              void* d_out, int out_size, void* d_ws, size_t ws_size,
                              hipStream_t stream) {
  const float* x        = (const float*)d_in[0];
  const float* W_ih_l0  = (const float*)d_in[1];
  const float* W_hh_l0  = (const float*)d_in[2];
  const float* b_ih_l0  = (const float*)d_in[3];
  const float* b_hh_l0  = (const float*)d_in[4];
  const float* W_ih_l0r = (const float*)d_in[5];
  const float* W_hh_l0r = (const float*)d_in[6];
  const float* b_ih_l0r = (const float*)d_in[7];
  const float* b_hh_l0r = (const float*)d_in[8];
  const float* W_ih_l1  = (const float*)d_in[9];
  const float* W_hh_l1  = (const float*)d_in[10];
  const float* b_ih_l1  = (const float*)d_in[11];
  const float* b_hh_l1  = (const float*)d_in[12];
  const float* W_ih_l1r = (const float*)d_in[13];
  const float* W_hh_l1r = (const float*)d_in[14];
  const float* b_ih_l1r = (const float*)d_in[15];
  const float* b_hh_l1r = (const float*)d_in[16];
  const float* W_lin    = (const float*)d_in[17];
  const float* b_lin    = (const float*)d_in[18];

  float* y0b = (float*)d_ws;   // [B][64][3][8] fp32 = 48 MB, shifted layout
  float* out = (float*)d_out;

  // K1: 8 lanes/batch -> 65536 threads = 1024 waves (1 wave/SIMD)
  lstm_l0_bwd<<<(B_ * 8) / 256, 256, 0, stream>>>(
      x, W_ih_l0r, W_hh_l0r, b_ih_l0r, b_hh_l0r, y0b);

  // K2: 8 lanes/batch -> 65536 threads = 1024 waves (1 wave/SIMD)
  lstm_fused_fwd<<<(B_ * 8) / 256, 256, 0, stream>>>(
      x, W_ih_l0, W_hh_l0, b_ih_l0, b_hh_l0,
      W_ih_l1, W_hh_l1, b_ih_l1, b_hh_l1,
      W_ih_l1r, W_hh_l1r, b_ih_l1r, b_hh_l1r,
      W_lin, b_lin, y0b, out);
}